// Round 4
// baseline (270.851 us; speedup 1.0000x reference)
//
#include <hip/hip_runtime.h>
#include <hip/hip_bf16.h>

#define CH 64
#define HW 3136
#define MTOT 401408   // 128*3136

// ---------------- K1: covariance partials ----------------
// 512 blocks * 784 pixels each (4 blocks per batch image). fp32 input.
// Deterministic in-block reduction, then fp32 atomics into global SR[4160].
__global__ __launch_bounds__(256) void k1_cov(const float* __restrict__ X,
                                              float* __restrict__ SR){
  __shared__ __align__(16) float tile[112*64];   // [p][c'] swizzled per 4-ch group
  __shared__ __align__(16) float outbuf[4096];
  const int t = threadIdx.x;
  const int blk = blockIdx.x;
  const float* Xb = X + (size_t)(blk >> 2)*(CH*HW) + (blk & 3)*784;
  const int tid = t & 31, ti = tid >> 2, tj = tid & 3, ps = t >> 5;

  int cc[7], pp[7];
#pragma unroll
  for (int k=0;k<7;++k){ int f4 = k*256 + t; cc[k] = f4/28; pp[k] = f4 - cc[k]*28; }

  float acc[8][16];
#pragma unroll
  for (int i=0;i<8;++i)
#pragma unroll
    for (int j=0;j<16;++j) acc[i][j] = 0.f;
  float sums[7] = {0.f,0.f,0.f,0.f,0.f,0.f,0.f};

  for (int tl=0; tl<7; ++tl){
    const float* src = Xb + tl*112;
    __syncthreads();
#pragma unroll
    for (int k=0;k<7;++k){
      const float4 v = *(const float4*)(src + (size_t)cc[k]*HW + 4*pp[k]);
      sums[k] += (v.x + v.y) + (v.z + v.w);
      const int s = pp[k] & 15;                                  // row-group swizzle
      const int colp = (((cc[k] >> 2) ^ s) << 2) | (cc[k] & 3);
      const int p = 4*pp[k];
      tile[(p+0)*64 + colp] = v.x;
      tile[(p+1)*64 + colp] = v.y;
      tile[(p+2)*64 + colp] = v.z;
      tile[(p+3)*64 + colp] = v.w;
    }
    __syncthreads();
    for (int pi=0; pi<14; ++pi){
      const int p = ps*14 + pi;
      const float* row = &tile[p*64];
      const int s = (p >> 2) & 15;
      const float4 va = *(const float4*)(row + (((2*ti+0) ^ s) << 2));
      const float4 vb = *(const float4*)(row + (((2*ti+1) ^ s) << 2));
      const float4 w0 = *(const float4*)(row + (((4*tj+0) ^ s) << 2));
      const float4 w1 = *(const float4*)(row + (((4*tj+1) ^ s) << 2));
      const float4 w2 = *(const float4*)(row + (((4*tj+2) ^ s) << 2));
      const float4 w3 = *(const float4*)(row + (((4*tj+3) ^ s) << 2));
      const float v[8]  = {va.x,va.y,va.z,va.w, vb.x,vb.y,vb.z,vb.w};
      const float wv[16] = {w0.x,w0.y,w0.z,w0.w, w1.x,w1.y,w1.z,w1.w,
                            w2.x,w2.y,w2.z,w2.w, w3.x,w3.y,w3.z,w3.w};
#pragma unroll
      for (int i=0;i<8;++i)
#pragma unroll
        for (int j=0;j<16;++j) acc[i][j] += v[i]*wv[j];
    }
  }
  // ---- deterministic cross-group reduction in LDS ----
  __syncthreads();                 // tile reads done; reuse tile as scratch
  float* csP = tile;               // csP[t*8 + k]
#pragma unroll
  for (int k=0;k<7;++k) csP[t*8 + k] = sums[k];
  for (int w=0; w<8; ++w){
    if (ps == w){
      if (w == 0){
#pragma unroll
        for (int i=0;i<8;++i)
#pragma unroll
          for (int j=0;j<16;++j) outbuf[(8*ti+i)*64 + 16*tj + j] = acc[i][j];
      } else {
#pragma unroll
        for (int i=0;i<8;++i)
#pragma unroll
          for (int j=0;j<16;++j) outbuf[(8*ti+i)*64 + 16*tj + j] += acc[i][j];
      }
    }
    __syncthreads();
  }
  // ---- global accumulation (SR pre-zeroed by memset) ----
#pragma unroll
  for (int k=0;k<16;++k) unsafeAtomicAdd(&SR[t + 256*k], outbuf[t + 256*k]);
  if (t < 64){
    // channel c gets contributions from f4 = 28c..28c+27 -> (k=f4>>8, t=f4&255)
    float s = 0.f;
#pragma unroll
    for (int j=0;j<28;++j){
      const int f4 = 28*t + j;
      s += csP[(f4 & 255)*8 + (f4 >> 8)];
    }
    unsafeAtomicAdd(&SR[4096 + t], s);
  }
}

// ---------------- K2: whitening matrix ----------------
// out = alpha*(a^T b) + beta_*aff ; a symmetric in all our uses.
__device__ __forceinline__ void mm_AtB(const float* a, const float* b, float* out,
                                       float alpha, const float* aff, float beta_){
  const int t = threadIdx.x;
  const int c2 = 2*(t & 31);
  const int r0 = 8*(t >> 5);
  float acc[8][2];
#pragma unroll
  for (int i=0;i<8;++i){ acc[i][0]=0.f; acc[i][1]=0.f; }
  for (int k=0;k<64;++k){
    const float2 bv = *(const float2*)&b[k*64 + c2];
    const float4 a0 = *(const float4*)&a[k*64 + r0];
    const float4 a1 = *(const float4*)&a[k*64 + r0 + 4];
    const float av[8] = {a0.x,a0.y,a0.z,a0.w, a1.x,a1.y,a1.z,a1.w};
#pragma unroll
    for (int i=0;i<8;++i){ acc[i][0] += av[i]*bv.x; acc[i][1] += av[i]*bv.y; }
  }
  float res[8][2];
#pragma unroll
  for (int i=0;i<8;++i){
    float f0 = alpha*acc[i][0], f1 = alpha*acc[i][1];
    if (aff){ f0 += beta_*aff[(r0+i)*64 + c2]; f1 += beta_*aff[(r0+i)*64 + c2 + 1]; }
    res[i][0]=f0; res[i][1]=f1;
  }
  __syncthreads();
#pragma unroll
  for (int i=0;i<8;++i){
    float2 o2; o2.x = res[i][0]; o2.y = res[i][1];
    *(float2*)&out[(r0+i)*64 + c2] = o2;
  }
  __syncthreads();
}

__global__ __launch_bounds__(256) void k2_wm(const float* __restrict__ SR,
                                             const float* __restrict__ beta,
                                             float* __restrict__ WM,
                                             float* __restrict__ OFS){
  __shared__ __align__(16) float bufE[4096];
  __shared__ __align__(16) float bufA[4096];
  __shared__ __align__(16) float bufB[4096];
  __shared__ float meanv[64];
  __shared__ float scal[2];
  const int t = threadIdx.x;
  const float inv_m = 1.f/(float)MTOT;
  if (t < 64) meanv[t] = SR[4096 + t]*inv_m;
  __syncthreads();
  // E = Sigma - I  (Sigma includes eps on diag and 0.9 off-diag fix)
  for (int idx=t; idx<4096; idx+=256){
    const int r = idx >> 6, c = idx & 63;
    const float cov = SR[idx]*inv_m - meanv[r]*meanv[c];
    bufE[idx] = (r==c) ? (cov + 1e-5f - 1.f) : 0.9f*cov;
  }
  __syncthreads();
  float n2 = 0.f, tr = 0.f;
  for (int idx=t; idx<4096; idx+=256){
    const float e = bufE[idx];
    n2 += e*e;
    if ((idx >> 6) == (idx & 63)) tr += e;
  }
  bufA[t] = n2; bufB[t] = tr;
  __syncthreads();
  if (t < 64){
    bufA[t] = bufA[t]+bufA[t+64]+bufA[t+128]+bufA[t+192];
    bufB[t] = bufB[t]+bufB[t+64]+bufB[t+128]+bufB[t+192];
  }
  __syncthreads();
  if (t == 0){
    float s1=0.f, s2=0.f;
    for (int i=0;i<64;++i){ s1 += bufA[i]; s2 += bufB[i]; }
    scal[0] = s1; scal[1] = s2;
  }
  __syncthreads();
  const float frob2 = scal[0];
  const float trE   = scal[1];
  float wscale = 1.f;
  const float* wmLds;
  if (frob2 < 0.04f){
    // ||E||_F < 0.2: NS at T=10 is machine-converged -> wm = (I+E)^(-1/2) via series
    mm_AtB(bufE, bufE, bufA, 1.f, nullptr, 0.f);   // E^2
    mm_AtB(bufA, bufE, bufB, 1.f, nullptr, 0.f);   // E^3
    for (int idx=t; idx<4096; idx+=256){
      const int r = idx >> 6, c = idx & 63;
      bufB[idx] = ((r==c)?1.f:0.f) - 0.5f*bufE[idx] + 0.375f*bufA[idx] - 0.3125f*bufB[idx];
    }
    mm_AtB(bufA, bufA, bufE, 1.f, nullptr, 0.f);   // E^4 (barrier-safe overwrite)
    for (int idx=t; idx<4096; idx+=256)
      bufB[idx] += 0.2734375f*bufE[idx];           // 35/128
    wmLds = bufB;
  } else {
    // robust fallback: exact Newton-Schulz, 10 iterations
    const float rTr = 1.f/(trE + 64.f);
    for (int idx=t; idx<4096; idx+=256){
      const int r = idx >> 6, c = idx & 63;
      bufE[idx] = (bufE[idx] + ((r==c)?1.f:0.f))*rTr;   // Sigma_N
      bufA[idx] = (r==c)?1.f:0.f;                        // P = I
    }
    __syncthreads();
    for (int it=0; it<10; ++it){
      mm_AtB(bufA, bufE, bufB, 1.f, nullptr, 0.f);   // T1 = P@SigmaN
      mm_AtB(bufA, bufB, bufB, 1.f, nullptr, 0.f);   // T2 = P@T1
      mm_AtB(bufA, bufB, bufA, -0.5f, bufA, 1.5f);   // P = 1.5P - 0.5*P@T2
    }
    wscale = sqrtf(rTr);
    wmLds = bufA;
  }
  __syncthreads();
  for (int idx=t; idx<4096; idx+=256) WM[idx] = wmLds[idx]*wscale;
  if (t < 64){
    float d = 0.f;
    for (int j=0;j<64;++j) d += wmLds[t*64 + j]*meanv[j];
    OFS[t] = beta[t] - d*wscale;
  }
}

// ---------------- K3: apply whitening, write fp32 ----------------
__global__ __launch_bounds__(256) void k3_apply(const float* __restrict__ X,
                                                const float* __restrict__ WM,
                                                const float* __restrict__ OFS,
                                                float* __restrict__ out){
  __shared__ __align__(16) float tile[64*256];   // [c][p] natural layout
  const int t = threadIdx.x;
  const int w = __builtin_amdgcn_readfirstlane((int)(t >> 6));
  const int l = t & 63;
  const int pix = blockIdx.x*256 + 4*l;
  const int b = pix / HW;
  const int hw = pix - b*HW;
  const float* Xb = X + (size_t)b*(CH*HW) + hw;
#pragma unroll
  for (int k=0;k<16;++k){
    const int c = 4*k + w;
    const float4 v = *(const float4*)(Xb + (size_t)c*HW);
    *(float4*)&tile[c*256 + 4*l] = v;
  }
  __syncthreads();
  const int c0 = 16*w;
  float acc[16][4];
#pragma unroll
  for (int i=0;i<16;++i){ acc[i][0]=0.f; acc[i][1]=0.f; acc[i][2]=0.f; acc[i][3]=0.f; }
  for (int k=0;k<64;++k){
    const float4 xv = *(const float4*)&tile[k*256 + 4*l];
#pragma unroll
    for (int i=0;i<16;++i){
      const float wv = WM[(c0+i)*64 + k];   // wave-uniform -> s_load
      acc[i][0] += wv*xv.x; acc[i][1] += wv*xv.y;
      acc[i][2] += wv*xv.z; acc[i][3] += wv*xv.w;
    }
  }
  float* ob = out + (size_t)b*(CH*HW) + hw;
#pragma unroll
  for (int i=0;i<16;++i){
    const float o = OFS[c0+i];
    float4 pk;
    pk.x = acc[i][0]+o; pk.y = acc[i][1]+o;
    pk.z = acc[i][2]+o; pk.w = acc[i][3]+o;
    *(float4*)(ob + (size_t)(c0+i)*HW) = pk;
  }
}

extern "C" void kernel_launch(void* const* d_in, const int* in_sizes, int n_in,
                              void* d_out, int out_size, void* d_ws, size_t ws_size,
                              hipStream_t stream){
  const float* X    = (const float*)d_in[0];
  const float* beta = (const float*)d_in[1];
  float* out = (float*)d_out;
  float* ws  = (float*)d_ws;
  float* SR  = ws;            // 4160 floats (4096 raw moments + 64 channel sums)
  float* WM  = ws + 4160;     // 4096
  float* OFS = WM + 4096;     // 64
  hipMemsetAsync(SR, 0, 4160*sizeof(float), stream);
  hipLaunchKernelGGL(k1_cov,   dim3(512),  dim3(256), 0, stream, X, SR);
  hipLaunchKernelGGL(k2_wm,    dim3(1),    dim3(256), 0, stream, SR, beta, WM, OFS);
  hipLaunchKernelGGL(k3_apply, dim3(1568), dim3(256), 0, stream, X, WM, OFS, out);
}